// Round 8
// baseline (726.291 us; speedup 1.0000x reference)
//
#include <hip/hip_runtime.h>
#include <math.h>

#define NV 10000
#define B 512
#define L 256
#define E 64

typedef _Float16 f16;
typedef _Float16 f16x8 __attribute__((ext_vector_type(8)));
typedef float f32x4 __attribute__((ext_vector_type(4)));
typedef int v8i __attribute__((ext_vector_type(8)));

// ws layout (f32 offsets)
#define OFF_WA1HT 0u         // [256][256] f32  Wa1hT[k*256+j] = Wa1[j*512+k]
#define OFF_WC1T  65536u     // [256][256] f32
#define OFF_WB    131072u    // 262144 B: fp8 frags of 8*W_hh for mfma_scale 16x16x128
#define OFF_WIHF  196608u    // 262144 f16: frags of W_ih (16x16x32 f16 layout)
#define OFF_WA1NF 327680u    // 65536 f16: frags of Wa1n
#define OFF_PEMB  360448u    // 10,240,000 f32: P_perm[v][hc*4+q] = 0.5*(ge@W_ih^T+b)[v][q*256+hc]
#define OFF_AEMB  10600448u  // 2,560,000 f16: A_emb[v][256]
// total 11,880,448 f32 = 47.5 MB

__device__ __forceinline__ int fp8_byte(float x) {
  return __builtin_amdgcn_cvt_pk_fp8_f32(x, x, 0, false) & 0xFF;
}
__device__ __forceinline__ unsigned int fp8_pk(float x, float y) {
  return (unsigned int)__builtin_amdgcn_cvt_pk_fp8_f32(x, y, 0, false);
}

// scale_b = 120 (e8m0) => product * 2^-7: gates = P + (16h)*(8W)/128
#define MFMA_SC(a, b, c) \
  __builtin_amdgcn_mfma_scale_f32_16x16x128_f8f6f4((a), (b), (c), 0, 0, 0, 127, 0, 120)

__global__ __launch_bounds__(256) void k_prep(
    const float* __restrict__ W_ih, const float* __restrict__ W_hh,
    const float* __restrict__ Wa1, const float* __restrict__ Wc1,
    float* __restrict__ ws) {
  int idx = blockIdx.x * 256 + threadIdx.x;
  if (idx < 65536) {  // W_hh fp8 frags (x8) for 16x16x128: dword idx
    int d = idx & 7, lane = (idx >> 3) & 63, kt = (idx >> 9) & 1;
    int q = (idx >> 10) & 3, w = (idx >> 12) & 15;
    int l15 = lane & 15, quad = lane >> 4;
    int n = q * 256 + w * 16 + l15;
    int kb = kt * 128 + quad * 32 + d * 4;
    unsigned int word = 0;
#pragma unroll
    for (int jb = 0; jb < 4; ++jb)
      word |= ((unsigned int)fp8_byte(W_hh[n * 256 + kb + jb] * 8.f)) << (8 * jb);
    ((unsigned int*)(ws + OFF_WB))[idx] = word;
    return;
  }
  int p1 = idx - 65536;
  if (p1 < 262144) {  // W_ih f16 frags (16x16x32 layout, for k_pemb)
    int j = p1 & 7, lane = (p1 >> 3) & 63, kt = (p1 >> 9) & 7;
    int q = (p1 >> 12) & 3, w = (p1 >> 14) & 15;
    int n = q * 256 + w * 16 + (lane & 15);
    int k = kt * 32 + (lane >> 4) * 8 + j;
    ((f16*)(ws + OFF_WIHF))[p1] = (f16)W_ih[n * 256 + k];
    return;
  }
  int p2 = p1 - 262144;
  if (p2 < 65536) {  // Wa1n f16 frags
    int j = p2 & 7, lane = (p2 >> 3) & 63, kt = (p2 >> 9) & 7, w = (p2 >> 12) & 15;
    int n = w * 16 + (lane & 15);
    int k = kt * 32 + (lane >> 4) * 8 + j;
    ((f16*)(ws + OFF_WA1NF))[p2] = (f16)Wa1[n * 512 + 256 + k];
    return;
  }
  int i2 = p2 - 65536;
  if (i2 < 65536) {  // actor/critic transposes
    int k = i2 >> 8, j = i2 & 255;
    ws[OFF_WA1HT + i2] = Wa1[j * 512 + k];
    ws[OFF_WC1T + i2] = Wc1[j * 256 + k];
  }
}

// Fused P_emb + A_emb via f16 MFMA. 32 vertices/block, 1024 threads.
// P stored pre-halved: each of the two MFMA planes contributes 0.5*P.
__global__ __launch_bounds__(1024) void k_pemb(
    const float* __restrict__ ge, const float* __restrict__ b_ih,
    const float* __restrict__ b_hh, float* __restrict__ ws) {
  __shared__ f16 Alds[32 * 264];
  const int tid = threadIdx.x, w = tid >> 6, lane = tid & 63;
  const int l15 = lane & 15, quad = lane >> 4;
  const int vbase = blockIdx.x * 32;
  for (int i = tid; i < 32 * 256; i += 1024) {
    int row = i >> 8, col = i & 255;
    int v = min(vbase + row, NV - 1);
    Alds[row * 264 + col] = (f16)ge[(size_t)v * 256 + col];
  }
  __syncthreads();
  const f16* __restrict__ WIHF = (const f16*)(ws + OFF_WIHF);
  const f16* __restrict__ WANF = (const f16*)(ws + OFF_WA1NF);
  f32x4 Cp[2][4], Ca[2];
#pragma unroll
  for (int t = 0; t < 2; ++t) {
    Ca[t] = (f32x4){0.f, 0.f, 0.f, 0.f};
#pragma unroll
    for (int q = 0; q < 4; ++q) Cp[t][q] = (f32x4){0.f, 0.f, 0.f, 0.f};
  }
#pragma unroll
  for (int kt = 0; kt < 8; ++kt) {
    f16x8 a0 = *(const f16x8*)(Alds + l15 * 264 + kt * 32 + quad * 8);
    f16x8 a1 = *(const f16x8*)(Alds + (l15 + 16) * 264 + kt * 32 + quad * 8);
#pragma unroll
    for (int q = 0; q < 4; ++q) {
      f16x8 bq = *(const f16x8*)(WIHF + (size_t)(((w * 4 + q) * 8 + kt) * 512 + lane * 8));
      Cp[0][q] = __builtin_amdgcn_mfma_f32_16x16x32_f16(a0, bq, Cp[0][q], 0, 0, 0);
      Cp[1][q] = __builtin_amdgcn_mfma_f32_16x16x32_f16(a1, bq, Cp[1][q], 0, 0, 0);
    }
    f16x8 bn = *(const f16x8*)(WANF + (size_t)((w * 8 + kt) * 512 + lane * 8));
    Ca[0] = __builtin_amdgcn_mfma_f32_16x16x32_f16(a0, bn, Ca[0], 0, 0, 0);
    Ca[1] = __builtin_amdgcn_mfma_f32_16x16x32_f16(a1, bn, Ca[1], 0, 0, 0);
  }
  const int hc = w * 16 + l15;
  float bias[4];
#pragma unroll
  for (int q = 0; q < 4; ++q) {
    int n = q * 256 + hc;
    bias[q] = b_ih[n] + b_hh[n];
  }
  float* __restrict__ P = ws + OFF_PEMB;
  f16* __restrict__ A = (f16*)(ws + OFF_AEMB);
#pragma unroll
  for (int tile = 0; tile < 2; ++tile)
#pragma unroll
    for (int reg = 0; reg < 4; ++reg) {
      int v = vbase + tile * 16 + quad * 4 + reg;
      if (v < NV) {
        f32x4 pw;
#pragma unroll
        for (int q = 0; q < 4; ++q) pw[q] = 0.5f * (Cp[tile][q][reg] + bias[q]);
        *(f32x4*)(P + (size_t)v * 1024 + hc * 4) = pw;
        A[(size_t)v * 256 + hc] = (f16)Ca[tile][reg];
      }
    }
}

// LSTM + fused heads: 64 blocks x 1024 threads, G=8 paths/block.
// hA rows 0-7 = fp8(16h) hi, rows 8-15 = fp8 residual. Both planes init 0.5P;
// shfl_xor(32) combine reconstructs P + h.W (scale_b=2^-7 folds the /128).
__global__ __launch_bounds__(1024) void k_lstm(
    const int* __restrict__ paths, const int* __restrict__ path_lens,
    const int* __restrict__ neighbors, const int* __restrict__ n_nb,
    const float* __restrict__ ba1, const float* __restrict__ Wa2,
    const float* __restrict__ ba2, const float* __restrict__ bc1,
    const float* __restrict__ Wc2, const float* __restrict__ bc2,
    float* __restrict__ out, float* __restrict__ ws) {
  const int tid = threadIdx.x, w = tid >> 6, lane = tid & 63;
  const int l15 = lane & 15, quad = lane >> 4;
  const int g8 = blockIdx.x * 8;

  __shared__ char hA[2][16 * 272];   // [parity][row*272 + k] fp8
  __shared__ int plds[8][256];       // path vertex lists
  __shared__ int red8[8];
  __shared__ float hfin[8][257];
  __shared__ float u_s[8][256];
  __shared__ float part_s[8][64][2];
  __shared__ float vred[8][132];

  for (int i = tid; i < 2176; i += 1024) ((int*)hA)[i] = 0;
  for (int i = tid; i < 2048; i += 1024)
    plds[i >> 8][i & 255] = paths[(g8 + (i >> 8)) * L + (i & 255)];
  if (tid < 8) red8[tid] = path_lens[g8 + tid];
  __syncthreads();
  int lmax = 0;
#pragma unroll
  for (int i = 0; i < 8; ++i) lmax = max(lmax, red8[i]);

  // persistent B-frags for mfma_scale 16x16x128 (64 VGPR)
  const v8i* __restrict__ WBv = (const v8i*)(ws + OFF_WB);
  v8i Bf[4][2];
#pragma unroll
  for (int q = 0; q < 4; ++q)
#pragma unroll
    for (int kt = 0; kt < 2; ++kt)
      Bf[q][kt] = WBv[(size_t)(((w * 4 + q) * 2 + kt) * 64 + lane)];

  const float* __restrict__ Pf = ws + OFF_PEMB;
  const int hc = w * 16 + l15;

  // lane's C rows: quad*4+r; path = row&7
  int prow[4], v4[4];
#pragma unroll
  for (int r = 0; r < 4; ++r) {
    prow[r] = (quad * 4 + r) & 7;
    v4[r] = plds[prow[r]][0];
  }
  f32x4 pv[4];
#pragma unroll
  for (int r = 0; r < 4; ++r)
    pv[r] = *(const f32x4*)(Pf + (size_t)v4[r] * 1024 + hc * 4);

  // cell ownership: p0,p1
  const int rsel = (quad >> 1) * 2;          // 0 or 2
  const int p0 = (quad & 1) * 4 + rsel, p1 = p0 + 1;
  const int len0 = red8[p0], len1 = red8[p1];
  float c0 = 0.f, c1 = 0.f, h0 = 0.f, h1 = 0.f;

  // byte-transpose constants (4x4 across lanes l15%4)
  const unsigned int sel1 = (l15 & 1) ? 0x07030602u : 0x01050004u;
  const unsigned int sel2 = (l15 & 2) ? 0x07060302u : 0x01000504u;
  const int rowW = p0 + ((l15 >> 1) & 1) + ((l15 & 1) << 3);
  const int wcol = w * 16 + (l15 & ~3);

  for (int t = 0; t < lmax; ++t) {
    f32x4 Cf[4];
#pragma unroll
    for (int q = 0; q < 4; ++q)
#pragma unroll
      for (int r = 0; r < 4; ++r) Cf[q][r] = pv[r][q];
    const int t1 = min(t + 1, L - 1);
#pragma unroll
    for (int r = 0; r < 4; ++r) v4[r] = plds[prow[r]][t1];

    const char* hp = hA[t & 1];
#pragma unroll
    for (int kt = 0; kt < 2; ++kt) {
      const v8i a = *(const v8i*)(hp + l15 * 272 + kt * 128 + quad * 32);
#pragma unroll
      for (int q = 0; q < 4; ++q) Cf[q] = MFMA_SC(a, Bf[q][kt], Cf[q]);
    }
    // prefetch next P
#pragma unroll
    for (int r = 0; r < 4; ++r)
      pv[r] = *(const f32x4*)(Pf + (size_t)v4[r] * 1024 + hc * 4);

    // hi+lo combine: keep own needed regs, send partner's needed regs
    float G0[4], G1[4];
#pragma unroll
    for (int q = 0; q < 4; ++q) {
      const float k0 = rsel ? Cf[q][2] : Cf[q][0];
      const float s0 = rsel ? Cf[q][0] : Cf[q][2];
      const float k1 = rsel ? Cf[q][3] : Cf[q][1];
      const float s1 = rsel ? Cf[q][1] : Cf[q][3];
      G0[q] = k0 + __shfl_xor(s0, 32, 64);
      G1[q] = k1 + __shfl_xor(s1, 32, 64);
    }
    if (t < len0) {
      const float si = __builtin_amdgcn_rcpf(1.f + __expf(-G0[0]));
      const float sf = __builtin_amdgcn_rcpf(1.f + __expf(-G0[1]));
      const float tg = 1.f - 2.f * __builtin_amdgcn_rcpf(__expf(2.f * G0[2]) + 1.f);
      const float so = __builtin_amdgcn_rcpf(1.f + __expf(-G0[3]));
      c0 = sf * c0 + si * tg;
      h0 = so * (1.f - 2.f * __builtin_amdgcn_rcpf(__expf(2.f * c0) + 1.f));
    }
    if (t < len1) {
      const float si = __builtin_amdgcn_rcpf(1.f + __expf(-G1[0]));
      const float sf = __builtin_amdgcn_rcpf(1.f + __expf(-G1[1]));
      const float tg = 1.f - 2.f * __builtin_amdgcn_rcpf(__expf(2.f * G1[2]) + 1.f);
      const float so = __builtin_amdgcn_rcpf(1.f + __expf(-G1[3]));
      c1 = sf * c1 + si * tg;
      h1 = so * (1.f - 2.f * __builtin_amdgcn_rcpf(__expf(2.f * c1) + 1.f));
    }
    // pack fp8 hi/lo for both cells, 4x4 byte-transpose, single b32 write
    {
      const unsigned int hp2 = fp8_pk(16.f * h0, 16.f * h1);
      const float d0 = __builtin_amdgcn_cvt_f32_fp8((int)hp2, 0);
      const float d1 = __builtin_amdgcn_cvt_f32_fp8((int)hp2, 1);
      const unsigned int lp2 = fp8_pk(16.f * h0 - d0, 16.f * h1 - d1);
      unsigned int x = (hp2 & 0xFFFFu) | (lp2 << 16);
      unsigned int y = (unsigned int)__shfl_xor((int)x, 1, 64);
      unsigned int u = __builtin_amdgcn_perm(x, y, sel1);
      unsigned int v = (unsigned int)__shfl_xor((int)u, 2, 64);
      unsigned int z = __builtin_amdgcn_perm(u, v, sel2);
      char* nh = hA[(t + 1) & 1];
      *(unsigned int*)(nh + rowW * 272 + wcol) = z;
    }
    __syncthreads();
  }

  // ---- fused heads for this block's 8 paths ----
  hfin[p0][hc] = h0;
  hfin[p1][hc] = h1;
  __syncthreads();

  const float* __restrict__ Wa1hT = ws + OFF_WA1HT;
  const float* __restrict__ Wc1T = ws + OFF_WC1T;
  const int p = tid >> 7, jj = tid & 127;
  float aa0 = ba1[jj], aa1 = ba1[jj + 128];
  float cc0 = bc1[jj], cc1 = bc1[jj + 128];
  for (int k = 0; k < 256; ++k) {
    const float hk = hfin[p][k];
    aa0 += Wa1hT[k * 256 + jj] * hk;
    aa1 += Wa1hT[k * 256 + jj + 128] * hk;
    cc0 += Wc1T[k * 256 + jj] * hk;
    cc1 += Wc1T[k * 256 + jj + 128] * hk;
  }
  u_s[p][jj] = aa0;
  u_s[p][jj + 128] = aa1;
  cc0 = cc0 > 0.f ? cc0 : expm1f(cc0);
  cc1 = cc1 > 0.f ? cc1 : expm1f(cc1);
  vred[p][jj] = cc0 * Wc2[jj] + cc1 * Wc2[jj + 128];
  __syncthreads();
  if (tid < 512) {
    const int pp = tid >> 6, lp = tid & 63;
    float s = vred[pp][lp] + vred[pp][lp + 64];
#pragma unroll
    for (int d = 32; d > 0; d >>= 1) s += __shfl_xor(s, d, 64);
    if (lp == 0) out[B * E + g8 + pp] = s + bc2[0];
  }
  // actor logits
  const f16* __restrict__ A = (const f16*)(ws + OFF_AEMB);
  const int e = tid & 63, jh = (tid >> 6) & 1;
  const int nbv = neighbors[(g8 + p) * 64 + e];
  float s = 0.f;
  const int jb = jh * 128;
  for (int j2 = 0; j2 < 128; ++j2) {
    const int j = jb + j2;
    float a = u_s[p][j] + (float)A[(size_t)nbv * 256 + j];
    a = a > 0.f ? a : expm1f(a);
    s += a * Wa2[j];
  }
  part_s[p][e][jh] = s;
  __syncthreads();
  if (tid < 512) {
    const int pp = tid >> 6, ee = tid & 63;
    const int ne = n_nb[g8 + pp];
    const bool valid = ee < ne;
    float le = valid ? (part_s[pp][ee][0] + part_s[pp][ee][1] + ba2[0]) : -1e30f;
    float m = le;
#pragma unroll
    for (int d = 32; d > 0; d >>= 1) m = fmaxf(m, __shfl_xor(m, d, 64));
    float pe = valid ? __expf(le - m) : 0.f;
    float sm = pe;
#pragma unroll
    for (int d = 32; d > 0; d >>= 1) sm += __shfl_xor(sm, d, 64);
    out[(g8 + pp) * 64 + ee] = pe / sm;
  }
}

extern "C" void kernel_launch(void* const* d_in, const int* in_sizes, int n_in,
                              void* d_out, int out_size, void* d_ws, size_t ws_size,
                              hipStream_t stream) {
  (void)in_sizes; (void)n_in; (void)out_size; (void)ws_size;
  const float* graph_emb = (const float*)d_in[0];
  const int* paths       = (const int*)d_in[1];
  const int* path_lens   = (const int*)d_in[2];
  const int* neighbors   = (const int*)d_in[3];
  const int* n_nb        = (const int*)d_in[4];
  const float* W_ih = (const float*)d_in[5];
  const float* W_hh = (const float*)d_in[6];
  const float* b_ih = (const float*)d_in[7];
  const float* b_hh = (const float*)d_in[8];
  const float* Wa1  = (const float*)d_in[9];
  const float* ba1  = (const float*)d_in[10];
  const float* Wa2  = (const float*)d_in[11];
  const float* ba2  = (const float*)d_in[12];
  const float* Wc1  = (const float*)d_in[13];
  const float* bc1  = (const float*)d_in[14];
  const float* Wc2  = (const float*)d_in[15];
  const float* bc2  = (const float*)d_in[16];
  float* out = (float*)d_out;
  float* ws = (float*)d_ws;

  hipLaunchKernelGGL(k_prep, dim3(1792), dim3(256), 0, stream, W_ih, W_hh, Wa1, Wc1, ws);
  hipLaunchKernelGGL(k_pemb, dim3(313), dim3(1024), 0, stream, graph_emb, b_ih, b_hh, ws);
  hipLaunchKernelGGL(k_lstm, dim3(64), dim3(1024), 0, stream, paths, path_lens,
                     neighbors, n_nb, ba1, Wa2, ba2, bc1, Wc2, bc2, out, ws);
}